// Round 19
// baseline (2016.354 us; speedup 1.0000x reference)
//
#include <hip/hip_runtime.h>
#include <hip/hip_fp16.h>

// LSTM: B=256, S=4096, D=64, H=128 (4H=512 gate cols [i|f|g|o]).
// One batch element per block (256 blocks = 1/CU), 256 threads = 4 waves.
// R18 structure (x-projection hoisted into a chunked look-ahead GEMM; per
// step only 32 h-MFMA/SIMD) + this round:
//   1. XG row stride padded 512 -> 520 floats (row offset 8 banks): kills
//      the 4-way bank conflict on XG stores/reads.
//   2. xg+bias pre-adds folded mid-MFMA-stream (loads returned by then).
//   3. kk3 block staged with combine slices at >=4-issue producer distance:
//      kk3 n0-3 | pre-adds | kk3 n4,5 | zi,zf | kk3 n6,7 | iv,fv,zg |
//      zo,gv,ov | c/h chain. Starts the trans chain ~100 cyc earlier
//      without R15's latency-stall mistake.
// Per-column h-chain bits identical to R18; z-assoc differs ~1 ulp.

#define LSTM_B 256
#define LSTM_S 4096
#define LSTM_D 64
#define LSTM_H 128
#define LSTM_G 512
#define CHS 32
#define XGP 520
#define XG_BYTES (2 * CHS * XGP * 4)
#define SMEM_BYTES (XG_BYTES + 512 + 16 + 512)

typedef _Float16 f16x8 __attribute__((ext_vector_type(8)));
typedef float f32x4 __attribute__((ext_vector_type(4)));

#define SBAR() __builtin_amdgcn_sched_barrier(0)
#define MFM(A_, B_, C_) __builtin_amdgcn_mfma_f32_16x16x32_f16(A_, B_, C_, 0, 0, 0)

__device__ __forceinline__ float sigm(float z) {
  return __builtin_amdgcn_rcpf(1.0f + __builtin_amdgcn_exp2f(-1.44269504f * z));
}
__device__ __forceinline__ float tanh_(float z) {
  return 1.0f - 2.0f * __builtin_amdgcn_rcpf(1.0f + __builtin_amdgcn_exp2f(2.88539008f * z));
}
__device__ __forceinline__ f16x8 cvt8(float4 lo, float4 hi) {
  f16x8 r;
  r[0] = (_Float16)lo.x; r[1] = (_Float16)lo.y; r[2] = (_Float16)lo.z; r[3] = (_Float16)lo.w;
  r[4] = (_Float16)hi.x; r[5] = (_Float16)hi.y; r[6] = (_Float16)hi.z; r[7] = (_Float16)hi.w;
  return r;
}

__global__ __launch_bounds__(256, 1)
void lstm_mfma_kernel(const float* __restrict__ x,
                      const float* __restrict__ Wi,
                      const float* __restrict__ Wh,
                      const float* __restrict__ bh,
                      const float* __restrict__ Wo,
                      const float* __restrict__ bo,
                      float* __restrict__ out) {
  const int t    = threadIdx.x;      // 0..255
  const int lane = t & 63;
  const int w    = t >> 6;           // wave 0..3
  const int b    = blockIdx.x;
  const int lmod = lane & 15;
  const int lgrp = lane >> 4;

  extern __shared__ char smem[];
  float*    XGb = (float*)smem;                          // [2][CHS][XGP] fp32
  _Float16* Hb  = (_Float16*)(smem + XG_BYTES);          // [2][128]
  _Float16* Zr  = (_Float16*)(smem + XG_BYTES + 512);    // [8] zero region
  float*    Rr  = (float*)(smem + XG_BYTES + 512 + 16);  // [128] reduce

  // ---- B fragments: nt = 2g+hh -> cols n = 128g + 32w + 16hh + lmod ----
  f16x8 Bf[8][4], Bfx[8][2];
  #pragma unroll
  for (int g = 0; g < 4; ++g) {
    #pragma unroll
    for (int hh = 0; hh < 2; ++hh) {
      const int nt = 2 * g + hh;
      const int n = 128 * g + 32 * w + 16 * hh + lmod;
      #pragma unroll
      for (int kk = 0; kk < 4; ++kk) {
        union { f16x8 v; _Float16 e[8]; } u;
        #pragma unroll
        for (int j = 0; j < 8; ++j)
          u.e[j] = (_Float16)Wh[(size_t)(32 * kk + 8 * lgrp + j) * LSTM_G + n];
        Bf[nt][kk] = u.v;
      }
      #pragma unroll
      for (int kk = 0; kk < 2; ++kk) {
        union { f16x8 v; _Float16 e[8]; } u;
        #pragma unroll
        for (int j = 0; j < 8; ++j)
          u.e[j] = (_Float16)Wi[(size_t)(32 * kk + 8 * lgrp + j) * LSTM_G + n];
        Bfx[nt][kk] = u.v;
      }
    }
  }

  const int ul = 32 * w + (lane & 31);
  const float bb0 = bh[ul];
  const float bb1 = bh[LSTM_H + ul];
  const float bb2 = bh[2 * LSTM_H + ul];
  const float bb3 = bh[3 * LSTM_H + ul];

  const float* xb = x + (size_t)b * (LSTM_S * LSTM_D);
  const bool areal = (lmod == 0) || (lmod == 4);
  const f32x4 ZQ = {0.f, 0.f, 0.f, 0.f};

  if (t < LSTM_H) Hb[t] = (_Float16)0.0f;    // h_0 = 0
  if (t < 8) Zr[t] = (_Float16)0.0f;

  #define XLOAD(DA, DB, ROW, KK)                                          \
    { const float* p_ = xb + (size_t)(ROW) * LSTM_D + 32 * (KK) + 8 * lgrp; \
      DA = *(const float4*)p_; DB = *(const float4*)(p_ + 4); }

  float4 xf00a, xf00b, xf01a, xf01b, xf10a, xf10b, xf11a, xf11b;

  // ---- prologue: chunk-0 XG -> XGb[0]; preload chunk-1 x frags ----
  {
    XLOAD(xf00a, xf00b, lmod, 0)      XLOAD(xf01a, xf01b, lmod, 1)
    XLOAD(xf10a, xf10b, 16 + lmod, 0) XLOAD(xf11a, xf11b, 16 + lmod, 1)
    f16x8 A00 = cvt8(xf00a, xf00b), A01 = cvt8(xf01a, xf01b);
    f16x8 A10 = cvt8(xf10a, xf10b), A11 = cvt8(xf11a, xf11b);
    #pragma unroll
    for (int nt = 0; nt < 8; ++nt) {
      f32x4 t0 = MFM(A00, Bfx[nt][0], ZQ); t0 = MFM(A01, Bfx[nt][1], t0);
      f32x4 t1 = MFM(A10, Bfx[nt][0], ZQ); t1 = MFM(A11, Bfx[nt][1], t1);
      const int nc = 128 * (nt >> 1) + 32 * w + 16 * (nt & 1) + lmod;
      #pragma unroll
      for (int r = 0; r < 4; ++r) {
        XGb[(4 * lgrp + r) * XGP + nc]      = t0[r];
        XGb[(16 + 4 * lgrp + r) * XGP + nc] = t1[r];
      }
    }
    XLOAD(xf00a, xf00b, 32 + lmod, 0) XLOAD(xf01a, xf01b, 32 + lmod, 1)
    XLOAD(xf10a, xf10b, 48 + lmod, 0) XLOAD(xf11a, xf11b, 48 + lmod, 1)
  }
  float c = 0.f, hval = 0.f;
  __syncthreads();

  // one step. P = s&1 (Hb parity).
  #define STEPB(P)                                                            \
  {                                                                           \
    const int sc = s & (CHS - 1);                                             \
    const int cb = (s >> 5) & 1;                                              \
    const float* xgrow = XGb + cb * (CHS * XGP) + sc * XGP;                   \
    const float xgi = xgrow[ul];                                              \
    const float xgf = xgrow[LSTM_H + ul];                                     \
    const float xgg = xgrow[2 * LSTM_H + ul];                                 \
    const float xgo = xgrow[3 * LSTM_H + ul];                                 \
    const char* ahB = areal ? ((const char*)(Hb + (P) * LSTM_H) + 16 * lgrp)  \
                            : (const char*)Zr;                                \
    const int ahS = areal ? 64 : 0;                                           \
    f16x8 Ah0 = *(const f16x8*)(ahB);                                         \
    f16x8 Ah1 = *(const f16x8*)(ahB + 1 * ahS);                               \
    f16x8 Ah2 = *(const f16x8*)(ahB + 2 * ahS);                               \
    f16x8 Ah3 = *(const f16x8*)(ahB + 3 * ahS);                               \
    SBAR();                                                                   \
    if (sc == 16) {  /* load x rows of chunk c+2 */                           \
      const int rb = ((s >> 5) + 2) * CHS;                                    \
      int r0 = rb + lmod;      if (r0 > LSTM_S - 1) r0 = LSTM_S - 1;          \
      int r1 = rb + 16 + lmod; if (r1 > LSTM_S - 1) r1 = LSTM_S - 1;          \
      XLOAD(xf00a, xf00b, r0, 0) XLOAD(xf01a, xf01b, r0, 1)                   \
      XLOAD(xf10a, xf10b, r1, 0) XLOAD(xf11a, xf11b, r1, 1)                   \
    }                                                                         \
    if (sc == 0) {   /* one-shot GEMM: XG of chunk c+1 -> buf (c+1)&1 */      \
      const int nb = ((s >> 5) + 1) & 1;                                      \
      f16x8 A00 = cvt8(xf00a, xf00b), A01 = cvt8(xf01a, xf01b);               \
      f16x8 A10 = cvt8(xf10a, xf10b), A11 = cvt8(xf11a, xf11b);               \
      float* pb = XGb + nb * (CHS * XGP);                                     \
      _Pragma("unroll")                                                       \
      for (int nt = 0; nt < 8; ++nt) {                                        \
        f32x4 t0 = MFM(A00, Bfx[nt][0], ZQ); t0 = MFM(A01, Bfx[nt][1], t0);   \
        f32x4 t1 = MFM(A10, Bfx[nt][0], ZQ); t1 = MFM(A11, Bfx[nt][1], t1);   \
        const int nc = 128 * (nt >> 1) + 32 * w + 16 * (nt & 1) + lmod;       \
        _Pragma("unroll")                                                     \
        for (int r = 0; r < 4; ++r) {                                         \
          pb[(4 * lgrp + r) * XGP + nc]      = t0[r];                         \
          pb[(16 + 4 * lgrp + r) * XGP + nc] = t1[r];                         \
        }                                                                     \
      }                                                                       \
    }                                                                         \
    SBAR();                                                                   \
    f32x4 accH[8];                                                            \
    _Pragma("unroll")                                                         \
    for (int n = 0; n < 8; ++n) accH[n] = MFM(Ah0, Bf[n][0], ZQ);             \
    _Pragma("unroll")                                                         \
    for (int n = 0; n < 8; ++n) accH[n] = MFM(Ah1, Bf[n][1], accH[n]);        \
    _Pragma("unroll")                                                         \
    for (int n = 0; n < 8; ++n) accH[n] = MFM(Ah2, Bf[n][2], accH[n]);        \
    SBAR();                                                                   \
    const bool hsel = (lane & 16) != 0;                                       \
    float zi, zf, zg, zo, iv, fv, gv, ov;                                     \
    float xgb0, xgb1, xgb2, xgb3;                                             \
    /* kk3 staged with combine (>=4-issue producer distance) */               \
    accH[0] = MFM(Ah3, Bf[0][3], accH[0]);                                    \
    accH[1] = MFM(Ah3, Bf[1][3], accH[1]);                                    \
    accH[2] = MFM(Ah3, Bf[2][3], accH[2]);                                    \
    accH[3] = MFM(Ah3, Bf[3][3], accH[3]);                                    \
    SBAR();                                                                   \
    xgb0 = xgi + bb0; xgb1 = xgf + bb1;                                       \
    xgb2 = xgg + bb2; xgb3 = xgo + bb3;                                       \
    SBAR();                                                                   \
    accH[4] = MFM(Ah3, Bf[4][3], accH[4]);                                    \
    accH[5] = MFM(Ah3, Bf[5][3], accH[5]);                                    \
    SBAR();                                                                   \
    zi = (hsel ? accH[1][0] : accH[0][0]) + xgb0;                             \
    zf = (hsel ? accH[3][0] : accH[2][0]) + xgb1;                             \
    SBAR();                                                                   \
    accH[6] = MFM(Ah3, Bf[6][3], accH[6]);                                    \
    accH[7] = MFM(Ah3, Bf[7][3], accH[7]);                                    \
    SBAR();                                                                   \
    iv = sigm(zi);                                                            \
    fv = sigm(zf);                                                            \
    zg = (hsel ? accH[5][0] : accH[4][0]) + xgb2;                             \
    SBAR();                                                                   \
    zo = (hsel ? accH[7][0] : accH[6][0]) + xgb3;                             \
    gv = tanh_(zg);                                                           \
    ov = sigm(zo);                                                            \
    c = fv * c + iv * gv;                                                     \
    hval = ov * tanh_(c);                                                     \
    if (lane < 32) Hb[((P) ^ 1) * LSTM_H + ul] = (_Float16)hval;              \
    __syncthreads();                                                          \
  }

  for (int s = 0; s < LSTM_S; s += 2) {
    STEPB(0)
    ++s;
    STEPB(1)
    --s;
  }
  #undef STEPB
  #undef XLOAD

  // ---- output: out[b] = h_last @ Wo + bo ----
  if (lane < 32) Rr[ul] = hval * Wo[ul];
  __syncthreads();
  if (t < 64) {
    float v = Rr[t] + Rr[t + 64];
    #pragma unroll
    for (int off = 32; off; off >>= 1) v += __shfl_down(v, off);
    if (t == 0) out[b] = v + bo[0];
  }
}

extern "C" void kernel_launch(void* const* d_in, const int* in_sizes, int n_in,
                              void* d_out, int out_size, void* d_ws, size_t ws_size,
                              hipStream_t stream) {
  const float* x  = (const float*)d_in[0];
  const float* Wi = (const float*)d_in[1];
  const float* Wh = (const float*)d_in[2];
  const float* bh = (const float*)d_in[3];
  const float* Wo = (const float*)d_in[4];
  const float* bo = (const float*)d_in[5];
  float* out = (float*)d_out;

  hipFuncSetAttribute((const void*)lstm_mfma_kernel,
                      hipFuncAttributeMaxDynamicSharedMemorySize, SMEM_BYTES);
  lstm_mfma_kernel<<<LSTM_B, 256, SMEM_BYTES, stream>>>(x, Wi, Wh, bh, Wo, bo, out);
}

// Round 20
// 1834.483 us; speedup vs baseline: 1.0991x; 1.0991x over previous
//
#include <hip/hip_runtime.h>
#include <hip/hip_fp16.h>

// LSTM: B=256, S=4096, D=64, H=128 (4H=512 gate cols [i|f|g|o]).
// One batch element per block (256 blocks = 1/CU), 256 threads = 4 waves.
// EXACT R18 structure (best, 1822 us): x-projection hoisted into a chunked
// look-ahead GEMM (XGb double buffer, 32-step chunks); per step only the
// h-part (32 MFMA/SIMD) + in-register combine + ONE barrier.
// Single change vs R18: XG row stride 512 -> 514 floats. 514 % 32 = 2, so
// rows 4 apart differ by 8 banks -> the chunk-GEMM stores' lgrp groups land
// on banks {0,8,16,24} (worst 2-way aliasing = free on CDNA4), instead of
// 4-way same-bank (512 % 8 == 0; R19's 520 % 8 == 0 fixed nothing).
// Addresses only — arithmetic identical to R18 -> bit-identical output.
// R15/R19 lesson: do NOT stage the final h-MFMA block with combine slices.

#define LSTM_B 256
#define LSTM_S 4096
#define LSTM_D 64
#define LSTM_H 128
#define LSTM_G 512
#define CHS 32
#define XGP 514
#define XG_BYTES (2 * CHS * XGP * 4)
#define SMEM_BYTES (XG_BYTES + 512 + 16 + 512)

typedef _Float16 f16x8 __attribute__((ext_vector_type(8)));
typedef float f32x4 __attribute__((ext_vector_type(4)));

#define SBAR() __builtin_amdgcn_sched_barrier(0)
#define MFM(A_, B_, C_) __builtin_amdgcn_mfma_f32_16x16x32_f16(A_, B_, C_, 0, 0, 0)

__device__ __forceinline__ float sigm(float z) {
  return __builtin_amdgcn_rcpf(1.0f + __builtin_amdgcn_exp2f(-1.44269504f * z));
}
__device__ __forceinline__ float tanh_(float z) {
  return 1.0f - 2.0f * __builtin_amdgcn_rcpf(1.0f + __builtin_amdgcn_exp2f(2.88539008f * z));
}
__device__ __forceinline__ f16x8 cvt8(float4 lo, float4 hi) {
  f16x8 r;
  r[0] = (_Float16)lo.x; r[1] = (_Float16)lo.y; r[2] = (_Float16)lo.z; r[3] = (_Float16)lo.w;
  r[4] = (_Float16)hi.x; r[5] = (_Float16)hi.y; r[6] = (_Float16)hi.z; r[7] = (_Float16)hi.w;
  return r;
}

__global__ __launch_bounds__(256, 1)
void lstm_mfma_kernel(const float* __restrict__ x,
                      const float* __restrict__ Wi,
                      const float* __restrict__ Wh,
                      const float* __restrict__ bh,
                      const float* __restrict__ Wo,
                      const float* __restrict__ bo,
                      float* __restrict__ out) {
  const int t    = threadIdx.x;      // 0..255
  const int lane = t & 63;
  const int w    = t >> 6;           // wave 0..3
  const int b    = blockIdx.x;
  const int lmod = lane & 15;
  const int lgrp = lane >> 4;

  extern __shared__ char smem[];
  float*    XGb = (float*)smem;                          // [2][CHS][XGP] fp32
  _Float16* Hb  = (_Float16*)(smem + XG_BYTES);          // [2][128]
  _Float16* Zr  = (_Float16*)(smem + XG_BYTES + 512);    // [8] zero region
  float*    Rr  = (float*)(smem + XG_BYTES + 512 + 16);  // [128] reduce

  // ---- B fragments: nt = 2g+hh -> cols n = 128g + 32w + 16hh + lmod ----
  // Bf (Wh, kk0..3) and Bfx (Wi, kk0..1); elem j -> k = 32kk + 8lgrp + j.
  f16x8 Bf[8][4], Bfx[8][2];
  #pragma unroll
  for (int g = 0; g < 4; ++g) {
    #pragma unroll
    for (int hh = 0; hh < 2; ++hh) {
      const int nt = 2 * g + hh;
      const int n = 128 * g + 32 * w + 16 * hh + lmod;
      #pragma unroll
      for (int kk = 0; kk < 4; ++kk) {
        union { f16x8 v; _Float16 e[8]; } u;
        #pragma unroll
        for (int j = 0; j < 8; ++j)
          u.e[j] = (_Float16)Wh[(size_t)(32 * kk + 8 * lgrp + j) * LSTM_G + n];
        Bf[nt][kk] = u.v;
      }
      #pragma unroll
      for (int kk = 0; kk < 2; ++kk) {
        union { f16x8 v; _Float16 e[8]; } u;
        #pragma unroll
        for (int j = 0; j < 8; ++j)
          u.e[j] = (_Float16)Wi[(size_t)(32 * kk + 8 * lgrp + j) * LSTM_G + n];
        Bfx[nt][kk] = u.v;
      }
    }
  }

  const int ul = 32 * w + (lane & 31);
  const float bb0 = bh[ul];
  const float bb1 = bh[LSTM_H + ul];
  const float bb2 = bh[2 * LSTM_H + ul];
  const float bb3 = bh[3 * LSTM_H + ul];

  const float* xb = x + (size_t)b * (LSTM_S * LSTM_D);
  const bool areal = (lmod == 0) || (lmod == 4);
  const f32x4 ZQ = {0.f, 0.f, 0.f, 0.f};

  if (t < LSTM_H) Hb[t] = (_Float16)0.0f;    // h_0 = 0
  if (t < 8) Zr[t] = (_Float16)0.0f;

  #define XLOAD(DA, DB, ROW, KK)                                          \
    { const float* p_ = xb + (size_t)(ROW) * LSTM_D + 32 * (KK) + 8 * lgrp; \
      DA = *(const float4*)p_; DB = *(const float4*)(p_ + 4); }

  float4 xf00a, xf00b, xf01a, xf01b, xf10a, xf10b, xf11a, xf11b;

  // ---- prologue: chunk-0 XG -> XGb[0]; preload chunk-1 x frags ----
  {
    XLOAD(xf00a, xf00b, lmod, 0)      XLOAD(xf01a, xf01b, lmod, 1)
    XLOAD(xf10a, xf10b, 16 + lmod, 0) XLOAD(xf11a, xf11b, 16 + lmod, 1)
    f16x8 A00 = cvt8(xf00a, xf00b), A01 = cvt8(xf01a, xf01b);
    f16x8 A10 = cvt8(xf10a, xf10b), A11 = cvt8(xf11a, xf11b);
    #pragma unroll
    for (int nt = 0; nt < 8; ++nt) {
      f32x4 t0 = MFM(A00, Bfx[nt][0], ZQ); t0 = MFM(A01, Bfx[nt][1], t0);
      f32x4 t1 = MFM(A10, Bfx[nt][0], ZQ); t1 = MFM(A11, Bfx[nt][1], t1);
      const int nc = 128 * (nt >> 1) + 32 * w + 16 * (nt & 1) + lmod;
      #pragma unroll
      for (int r = 0; r < 4; ++r) {
        XGb[(4 * lgrp + r) * XGP + nc]      = t0[r];
        XGb[(16 + 4 * lgrp + r) * XGP + nc] = t1[r];
      }
    }
    XLOAD(xf00a, xf00b, 32 + lmod, 0) XLOAD(xf01a, xf01b, 32 + lmod, 1)
    XLOAD(xf10a, xf10b, 48 + lmod, 0) XLOAD(xf11a, xf11b, 48 + lmod, 1)
  }
  float c = 0.f, hval = 0.f;
  __syncthreads();

  // one step. P = s&1 (Hb parity).
  #define STEPB(P)                                                            \
  {                                                                           \
    const int sc = s & (CHS - 1);                                             \
    const int cb = (s >> 5) & 1;                                              \
    const float* xgrow = XGb + cb * (CHS * XGP) + sc * XGP;                   \
    const float xgi = xgrow[ul];                                              \
    const float xgf = xgrow[LSTM_H + ul];                                     \
    const float xgg = xgrow[2 * LSTM_H + ul];                                 \
    const float xgo = xgrow[3 * LSTM_H + ul];                                 \
    const char* ahB = areal ? ((const char*)(Hb + (P) * LSTM_H) + 16 * lgrp)  \
                            : (const char*)Zr;                                \
    const int ahS = areal ? 64 : 0;                                           \
    f16x8 Ah0 = *(const f16x8*)(ahB);                                         \
    f16x8 Ah1 = *(const f16x8*)(ahB + 1 * ahS);                               \
    f16x8 Ah2 = *(const f16x8*)(ahB + 2 * ahS);                               \
    f16x8 Ah3 = *(const f16x8*)(ahB + 3 * ahS);                               \
    SBAR();                                                                   \
    if (sc == 16) {  /* load x rows of chunk c+2 */                           \
      const int rb = ((s >> 5) + 2) * CHS;                                    \
      int r0 = rb + lmod;      if (r0 > LSTM_S - 1) r0 = LSTM_S - 1;          \
      int r1 = rb + 16 + lmod; if (r1 > LSTM_S - 1) r1 = LSTM_S - 1;          \
      XLOAD(xf00a, xf00b, r0, 0) XLOAD(xf01a, xf01b, r0, 1)                   \
      XLOAD(xf10a, xf10b, r1, 0) XLOAD(xf11a, xf11b, r1, 1)                   \
    }                                                                         \
    if (sc == 0) {   /* one-shot GEMM: XG of chunk c+1 -> buf (c+1)&1 */      \
      const int nb = ((s >> 5) + 1) & 1;                                      \
      f16x8 A00 = cvt8(xf00a, xf00b), A01 = cvt8(xf01a, xf01b);               \
      f16x8 A10 = cvt8(xf10a, xf10b), A11 = cvt8(xf11a, xf11b);               \
      float* pb = XGb + nb * (CHS * XGP);                                     \
      _Pragma("unroll")                                                       \
      for (int nt = 0; nt < 8; ++nt) {                                        \
        f32x4 t0 = MFM(A00, Bfx[nt][0], ZQ); t0 = MFM(A01, Bfx[nt][1], t0);   \
        f32x4 t1 = MFM(A10, Bfx[nt][0], ZQ); t1 = MFM(A11, Bfx[nt][1], t1);   \
        const int nc = 128 * (nt >> 1) + 32 * w + 16 * (nt & 1) + lmod;       \
        _Pragma("unroll")                                                     \
        for (int r = 0; r < 4; ++r) {                                         \
          pb[(4 * lgrp + r) * XGP + nc]      = t0[r];                         \
          pb[(16 + 4 * lgrp + r) * XGP + nc] = t1[r];                         \
        }                                                                     \
      }                                                                       \
    }                                                                         \
    SBAR();                                                                   \
    f32x4 accH[8];                                                            \
    _Pragma("unroll")                                                         \
    for (int n = 0; n < 8; ++n) accH[n] = MFM(Ah0, Bf[n][0], ZQ);             \
    _Pragma("unroll")                                                         \
    for (int n = 0; n < 8; ++n) accH[n] = MFM(Ah1, Bf[n][1], accH[n]);        \
    _Pragma("unroll")                                                         \
    for (int n = 0; n < 8; ++n) accH[n] = MFM(Ah2, Bf[n][2], accH[n]);        \
    _Pragma("unroll")                                                         \
    for (int n = 0; n < 8; ++n) accH[n] = MFM(Ah3, Bf[n][3], accH[n]);        \
    {                                                                         \
      const bool hsel = (lane & 16) != 0;                                     \
      const float zi = (hsel ? accH[1][0] : accH[0][0]) + xgi + bb0;          \
      const float zf = (hsel ? accH[3][0] : accH[2][0]) + xgf + bb1;          \
      const float zg = (hsel ? accH[5][0] : accH[4][0]) + xgg + bb2;          \
      const float zo = (hsel ? accH[7][0] : accH[6][0]) + xgo + bb3;          \
      const float iv = sigm(zi);                                              \
      const float fv = sigm(zf);                                              \
      const float gv = tanh_(zg);                                             \
      const float ov = sigm(zo);                                              \
      c = fv * c + iv * gv;                                                   \
      hval = ov * tanh_(c);                                                   \
      if (lane < 32) Hb[((P) ^ 1) * LSTM_H + ul] = (_Float16)hval;            \
    }                                                                         \
    __syncthreads();                                                          \
  }

  for (int s = 0; s < LSTM_S; s += 2) {
    STEPB(0)
    ++s;
    STEPB(1)
    --s;
  }
  #undef STEPB
  #undef XLOAD

  // ---- output: out[b] = h_last @ Wo + bo ----
  if (lane < 32) Rr[ul] = hval * Wo[ul];
  __syncthreads();
  if (t < 64) {
    float v = Rr[t] + Rr[t + 64];
    #pragma unroll
    for (int off = 32; off; off >>= 1) v += __shfl_down(v, off);
    if (t == 0) out[b] = v + bo[0];
  }
}

extern "C" void kernel_launch(void* const* d_in, const int* in_sizes, int n_in,
                              void* d_out, int out_size, void* d_ws, size_t ws_size,
                              hipStream_t stream) {
  const float* x  = (const float*)d_in[0];
  const float* Wi = (const float*)d_in[1];
  const float* Wh = (const float*)d_in[2];
  const float* bh = (const float*)d_in[3];
  const float* Wo = (const float*)d_in[4];
  const float* bo = (const float*)d_in[5];
  float* out = (float*)d_out;

  hipFuncSetAttribute((const void*)lstm_mfma_kernel,
                      hipFuncAttributeMaxDynamicSharedMemorySize, SMEM_BYTES);
  lstm_mfma_kernel<<<LSTM_B, 256, SMEM_BYTES, stream>>>(x, Wi, Wh, bh, Wo, bo, out);
}